// Round 5
// baseline (1060.479 us; speedup 1.0000x reference)
//
#include <hip/hip_runtime.h>
#include <hip/hip_bf16.h>
#include <cstdint>
#include <cstddef>

// Dims (fixed by the reference)
#define BB 32     // batch
#define SC 64     // context length
#define TT 64     // decode steps
#define HH 256    // hidden
#define G3 768    // 3*H
#define VV 32000  // vocab

#define WSCL 16.f     // weight scale before fp8 quantization
#define VSCL 32.f     // vector (h/x/ctx) scale before fp8 quantization
#define INV512 (1.f / (WSCL * VSCL))

typedef float f32x4 __attribute__((ext_vector_type(4)));

__device__ __forceinline__ float sigmf(float x) { return 1.f / (1.f + __expf(-x)); }

// pack 8 consecutive fp32 (scaled by WSCL) into one fp8x8 fragment word
__device__ __forceinline__ unsigned long long pack_row8(const float* __restrict__ p) {
    int lo = 0, hi = 0;
    lo = __builtin_amdgcn_cvt_pk_fp8_f32(p[0] * WSCL, p[1] * WSCL, lo, false);
    lo = __builtin_amdgcn_cvt_pk_fp8_f32(p[2] * WSCL, p[3] * WSCL, lo, true);
    hi = __builtin_amdgcn_cvt_pk_fp8_f32(p[4] * WSCL, p[5] * WSCL, hi, false);
    hi = __builtin_amdgcn_cvt_pk_fp8_f32(p[6] * WSCL, p[7] * WSCL, hi, true);
    return ((unsigned long long)(unsigned int)hi << 32) | (unsigned long long)(unsigned int)lo;
}

// Declare one 16-row x 32-col fragment group (8 named longs) for row-tile `nm`.
// rowptr = &W[tile_row_base + rr][0]; per-lane k-offset = lg*8 within each kt*32.
#define DECL_ROW(nm, rowptr)                                 \
    const float* nm##_p = (rowptr) + (lg << 3);              \
    long nm##0 = (long)pack_row8(nm##_p + 0);                \
    long nm##1 = (long)pack_row8(nm##_p + 32);               \
    long nm##2 = (long)pack_row8(nm##_p + 64);               \
    long nm##3 = (long)pack_row8(nm##_p + 96);               \
    long nm##4 = (long)pack_row8(nm##_p + 128);              \
    long nm##5 = (long)pack_row8(nm##_p + 160);              \
    long nm##6 = (long)pack_row8(nm##_p + 192);              \
    long nm##7 = (long)pack_row8(nm##_p + 224);

// Accumulate one row-tile x full-K (8 MFMAs) against B-vector fragments in LDS.
#define MFMA_ROW(nm, bsrc, acc)                                                              \
    acc = __builtin_amdgcn_mfma_f32_16x16x32_fp8_fp8(nm##0, (long)(bsrc)[( 0) | lg], acc, 0, 0, 0); \
    acc = __builtin_amdgcn_mfma_f32_16x16x32_fp8_fp8(nm##1, (long)(bsrc)[( 4) | lg], acc, 0, 0, 0); \
    acc = __builtin_amdgcn_mfma_f32_16x16x32_fp8_fp8(nm##2, (long)(bsrc)[( 8) | lg], acc, 0, 0, 0); \
    acc = __builtin_amdgcn_mfma_f32_16x16x32_fp8_fp8(nm##3, (long)(bsrc)[(12) | lg], acc, 0, 0, 0); \
    acc = __builtin_amdgcn_mfma_f32_16x16x32_fp8_fp8(nm##4, (long)(bsrc)[(16) | lg], acc, 0, 0, 0); \
    acc = __builtin_amdgcn_mfma_f32_16x16x32_fp8_fp8(nm##5, (long)(bsrc)[(20) | lg], acc, 0, 0, 0); \
    acc = __builtin_amdgcn_mfma_f32_16x16x32_fp8_fp8(nm##6, (long)(bsrc)[(24) | lg], acc, 0, 0, 0); \
    acc = __builtin_amdgcn_mfma_f32_16x16x32_fp8_fp8(nm##7, (long)(bsrc)[(28) | lg], acc, 0, 0, 0);

// ---------------------------------------------------------------------------
// Kernel A: precompute GI_enc[s][b][g] = enc_emb[ctx[b][s]] . enc_Wih[g] + bih[g]
// (fp32, exact)
// ---------------------------------------------------------------------------
__global__ __launch_bounds__(256) void gi_pre_kernel(
    const int* __restrict__ ctx, const float* __restrict__ emb,
    const float* __restrict__ Wih, const float* __restrict__ bih,
    float* __restrict__ GI)
{
    __shared__ float4 xl[BB][HH / 4];
    __shared__ int tokl[BB];
    const int bid = blockIdx.x;
    const int s  = bid / 24;
    const int g0 = (bid % 24) * 32;
    const int t  = threadIdx.x;

    if (t < BB) tokl[t] = ctx[t * SC + s];
    __syncthreads();
    #pragma unroll
    for (int i = 0; i < 8; ++i) {
        int f = t + 256 * i;
        int b = f >> 6, c = f & 63;
        xl[b][c] = ((const float4*)(emb + (size_t)tokl[b] * HH))[c];
    }
    __syncthreads();

    const int gl = t & 31, bq = t >> 5;
    const float4* wr = (const float4*)(Wih + (size_t)(g0 + gl) * HH);
    float a0 = 0.f, a1 = 0.f, a2 = 0.f, a3 = 0.f;
    #pragma unroll 4
    for (int k = 0; k < HH / 4; ++k) {
        float4 w  = wr[k];
        float4 x0 = xl[bq * 4 + 0][k];
        float4 x1 = xl[bq * 4 + 1][k];
        float4 x2 = xl[bq * 4 + 2][k];
        float4 x3 = xl[bq * 4 + 3][k];
        a0 += w.x * x0.x + w.y * x0.y + w.z * x0.z + w.w * x0.w;
        a1 += w.x * x1.x + w.y * x1.y + w.z * x1.z + w.w * x1.w;
        a2 += w.x * x2.x + w.y * x2.y + w.z * x2.z + w.w * x2.w;
        a3 += w.x * x3.x + w.y * x3.y + w.z * x3.z + w.w * x3.w;
    }
    const float bv = bih[g0 + gl];
    GI[(size_t)(s * BB + bq * 4 + 0) * G3 + g0 + gl] = a0 + bv;
    GI[(size_t)(s * BB + bq * 4 + 1) * G3 + g0 + gl] = a1 + bv;
    GI[(size_t)(s * BB + bq * 4 + 2) * G3 + g0 + gl] = a2 + bv;
    GI[(size_t)(s * BB + bq * 4 + 3) * G3 + g0 + gl] = a3 + bv;
}

// ---------------------------------------------------------------------------
// Kernel B: full recurrence, one block per batch element (32 blocks x 768 thr).
// Gate matvecs via fp8 MFMA; weight fragments in NAMED scalar registers.
// ---------------------------------------------------------------------------
__global__ __launch_bounds__(768, 1) void seq_kernel(
    const int*   __restrict__ inp,
    const float* __restrict__ GI,
    const float* __restrict__ eWhh, const float* __restrict__ ebhh,
    const float* __restrict__ demb,
    const float* __restrict__ Wc,   const float* __restrict__ bc,
    const float* __restrict__ dWih, const float* __restrict__ dWhh,
    const float* __restrict__ dbih, const float* __restrict__ dbhh,
    const float* __restrict__ Wo,   const float* __restrict__ bo,
    float* __restrict__ out)
{
    __shared__ float eo[SC][HH];                       // 64 KB encoder outputs
    __shared__ unsigned long long wc2l[8192];          // 64 KB Wc2 fp8 frags
    __shared__ float h[HH];
    __shared__ float gg[G3];                           // gh raw (x512)
    __shared__ float gi2[G3];                          // gi raw (x512)
    __shared__ float sc[SC];
    __shared__ float ctxv[HH];
    __shared__ float xv[HH];
    __shared__ float xb[HH];
    __shared__ unsigned long long h_f8[32];            // h  * VSCL, fp8
    __shared__ unsigned long long c_f8[32];            // ctx* VSCL, fp8
    __shared__ unsigned long long x_f8[32];            // x  * VSCL, fp8
    __shared__ int tokl[TT];

    const int b    = blockIdx.x;
    const int t    = threadIdx.x;
    const int lane = t & 63;
    const int w    = t >> 6;          // wave id 0..11
    const int lg   = lane >> 4;       // k-group 0..3
    const int rr   = lane & 15;       // row within 16-row tile
    const bool wr0 = (rr == 0);

    if (t < TT) tokl[t] = inp[b * TT + t];

    // stage Wc2 (right half of W_comb) as fp8 fragments into LDS
    for (int i = t; i < 8192; i += 768) {
        const int lf = i & 63, kt = (i >> 6) & 7, rt2 = i >> 9;
        const float* p = Wc + (size_t)(rt2 * 16 + (lf & 15)) * (2 * HH)
                       + HH + kt * 32 + (lf >> 4) * 8;
        wc2l[i] = pack_row8(p);
    }

    // per-thread gate biases (t<256)
    float bi0 = 0.f, bi1 = 0.f, bi2 = 0.f, bh0 = 0.f, bh1 = 0.f, bh2 = 0.f;
    float eb0 = 0.f, eb1 = 0.f, eb2 = 0.f;
    if (t < HH) {
        bi0 = dbih[t]; bi1 = dbih[HH + t]; bi2 = dbih[2 * HH + t];
        bh0 = dbhh[t]; bh1 = dbhh[HH + t]; bh2 = dbhh[2 * HH + t];
        eb0 = ebhh[t]; eb1 = ebhh[HH + t]; eb2 = ebhh[2 * HH + t];
        // init h = 0 and xb[j] = b_comb[j] + emb_sos . W_comb[j, 0:256]  (fp32)
        h[t] = 0.f;
        float a = bc[t];
        const float4* wrp = (const float4*)(Wc + (size_t)t * (2 * HH));
        const float4* es  = (const float4*)(demb + HH);     // SOS_INDEX = 1
        #pragma unroll
        for (int k = 0; k < HH / 4; ++k) {
            float4 wv = wrp[k], e = es[k];
            a += wv.x * e.x + wv.y * e.y + wv.z * e.z + wv.w * e.w;
        }
        xb[t] = a;
    }

    // ================= encoder =================
    {
        // quantize this wave's eWhh rows into NAMED register fragments (64 VGPRs)
        DECL_ROW(aE0, eWhh + (size_t)((w << 6) +  0 + rr) * HH)
        DECL_ROW(aE1, eWhh + (size_t)((w << 6) + 16 + rr) * HH)
        DECL_ROW(aE2, eWhh + (size_t)((w << 6) + 32 + rr) * HH)
        DECL_ROW(aE3, eWhh + (size_t)((w << 6) + 48 + rr) * HH)

        // GI double-buffer: preload s = 0
        float g0 = 0.f, g1 = 0.f, g2 = 0.f;
        if (t < HH) {
            const float* gp = GI + (size_t)b * G3;
            g0 = gp[t]; g1 = gp[HH + t]; g2 = gp[2 * HH + t];
        }
        __syncthreads();

        for (int s = 0; s < SC; ++s) {
            float gn0 = 0.f, gn1 = 0.f, gn2 = 0.f;
            if (t < HH && s + 1 < SC) {
                const float* gp = GI + (size_t)((s + 1) * BB + b) * G3;
                gn0 = gp[t]; gn1 = gp[HH + t]; gn2 = gp[2 * HH + t];
            }
            if (t < 64) {   // pack h -> fp8 (x VSCL)
                int pk = 0;
                pk = __builtin_amdgcn_cvt_pk_fp8_f32(h[4*t]*VSCL,   h[4*t+1]*VSCL, pk, false);
                pk = __builtin_amdgcn_cvt_pk_fp8_f32(h[4*t+2]*VSCL, h[4*t+3]*VSCL, pk, true);
                ((unsigned int*)h_f8)[t] = (unsigned int)pk;
            }
            __syncthreads();
            // gh = Whh.h via MFMA (raw = 512x)
            {
                f32x4 acc = {0.f, 0.f, 0.f, 0.f};
                MFMA_ROW(aE0, h_f8, acc)
                if (wr0) *(f32x4*)(gg + (w << 6) +  0 + (lg << 2)) = acc;
            }
            {
                f32x4 acc = {0.f, 0.f, 0.f, 0.f};
                MFMA_ROW(aE1, h_f8, acc)
                if (wr0) *(f32x4*)(gg + (w << 6) + 16 + (lg << 2)) = acc;
            }
            {
                f32x4 acc = {0.f, 0.f, 0.f, 0.f};
                MFMA_ROW(aE2, h_f8, acc)
                if (wr0) *(f32x4*)(gg + (w << 6) + 32 + (lg << 2)) = acc;
            }
            {
                f32x4 acc = {0.f, 0.f, 0.f, 0.f};
                MFMA_ROW(aE3, h_f8, acc)
                if (wr0) *(f32x4*)(gg + (w << 6) + 48 + (lg << 2)) = acc;
            }
            __syncthreads();
            if (t < HH) {
                float r = sigmf(g0 + gg[t] * INV512 + eb0);
                float z = sigmf(g1 + gg[HH + t] * INV512 + eb1);
                float n = tanhf(g2 + r * (gg[2 * HH + t] * INV512 + eb2));
                float hn = (1.f - z) * n + z * h[t];
                h[t] = hn;
                eo[s][t] = hn;
            }
            g0 = gn0; g1 = gn1; g2 = gn2;
            __syncthreads();
        }
    }

    // ================= decoder =================
    // quantize this wave's dWih / dWhh rows into NAMED register fragments (128 VGPRs)
    DECL_ROW(aI0, dWih + (size_t)((w << 6) +  0 + rr) * HH)
    DECL_ROW(aI1, dWih + (size_t)((w << 6) + 16 + rr) * HH)
    DECL_ROW(aI2, dWih + (size_t)((w << 6) + 32 + rr) * HH)
    DECL_ROW(aI3, dWih + (size_t)((w << 6) + 48 + rr) * HH)
    DECL_ROW(aH0, dWhh + (size_t)((w << 6) +  0 + rr) * HH)
    DECL_ROW(aH1, dWhh + (size_t)((w << 6) + 16 + rr) * HH)
    DECL_ROW(aH2, dWhh + (size_t)((w << 6) + 32 + rr) * HH)
    DECL_ROW(aH3, dWhh + (size_t)((w << 6) + 48 + rr) * HH)

    for (int di = 0; di < TT; ++di) {
        // prefetch W_out[tok] row + b_out[tok] (consumed in D7)
        float4 wo = {0.f, 0.f, 0.f, 0.f};
        float bov = 0.f;
        if (t < 64) {
            const int tok = tokl[di];
            wo  = ((const float4*)(Wo + (size_t)tok * HH))[t];
            bov = bo[tok];
            // pack h -> fp8
            int pk = 0;
            pk = __builtin_amdgcn_cvt_pk_fp8_f32(h[4*t]*VSCL,   h[4*t+1]*VSCL, pk, false);
            pk = __builtin_amdgcn_cvt_pk_fp8_f32(h[4*t+2]*VSCL, h[4*t+3]*VSCL, pk, true);
            ((unsigned int*)h_f8)[t] = (unsigned int)pk;
        }
        __syncthreads();
        // D1: attention scores[s] = eo[s] . h  (fp32, 4 lanes per s, staggered)
        if (t < 256) {
            const int s = t >> 2, c = t & 3;
            float acc = 0.f;
            #pragma unroll 4
            for (int k = 0; k < 64; ++k) {
                int kk = ((k + s + c * 16) & 63) + c * 64;
                acc += eo[s][kk] * h[kk];
            }
            acc += __shfl_xor(acc, 1);
            acc += __shfl_xor(acc, 2);
            if (c == 0) sc[s] = acc;
        }
        __syncthreads();
        // D2: softmax over 64 scores
        if (t < 64) {
            float v = sc[t];
            float m = v;
            #pragma unroll
            for (int off = 32; off; off >>= 1) m = fmaxf(m, __shfl_xor(m, off));
            float e = __expf(v - m);
            float su = e;
            #pragma unroll
            for (int off = 32; off; off >>= 1) su += __shfl_xor(su, off);
            sc[t] = e / su;
        }
        __syncthreads();
        // D3: ctx[j] = sum_s attn[s] * eo[s][j]
        if (t < HH) {
            float a = 0.f;
            #pragma unroll 4
            for (int s = 0; s < SC; ++s) a += sc[s] * eo[s][t];
            ctxv[t] = a;
        }
        __syncthreads();
        if (t < 64) {  // pack ctx -> fp8
            int pk = 0;
            pk = __builtin_amdgcn_cvt_pk_fp8_f32(ctxv[4*t]*VSCL,   ctxv[4*t+1]*VSCL, pk, false);
            pk = __builtin_amdgcn_cvt_pk_fp8_f32(ctxv[4*t+2]*VSCL, ctxv[4*t+3]*VSCL, pk, true);
            ((unsigned int*)c_f8)[t] = (unsigned int)pk;
        }
        __syncthreads();
        // D4: x = relu(xb + Wc2.ctx) via MFMA on waves 0..7 (2 row-tiles each)
        if (w < 8) {
            #pragma unroll
            for (int i = 0; i < 2; ++i) {
                const int rt2 = (w << 1) + i;        // 0..15
                f32x4 acc = {0.f, 0.f, 0.f, 0.f};
                const unsigned long long* wrow = wc2l + (rt2 << 9);
                acc = __builtin_amdgcn_mfma_f32_16x16x32_fp8_fp8((long)wrow[(0<<6)|lane], (long)c_f8[( 0)|lg], acc, 0, 0, 0);
                acc = __builtin_amdgcn_mfma_f32_16x16x32_fp8_fp8((long)wrow[(1<<6)|lane], (long)c_f8[( 4)|lg], acc, 0, 0, 0);
                acc = __builtin_amdgcn_mfma_f32_16x16x32_fp8_fp8((long)wrow[(2<<6)|lane], (long)c_f8[( 8)|lg], acc, 0, 0, 0);
                acc = __builtin_amdgcn_mfma_f32_16x16x32_fp8_fp8((long)wrow[(3<<6)|lane], (long)c_f8[(12)|lg], acc, 0, 0, 0);
                acc = __builtin_amdgcn_mfma_f32_16x16x32_fp8_fp8((long)wrow[(4<<6)|lane], (long)c_f8[(16)|lg], acc, 0, 0, 0);
                acc = __builtin_amdgcn_mfma_f32_16x16x32_fp8_fp8((long)wrow[(5<<6)|lane], (long)c_f8[(20)|lg], acc, 0, 0, 0);
                acc = __builtin_amdgcn_mfma_f32_16x16x32_fp8_fp8((long)wrow[(6<<6)|lane], (long)c_f8[(24)|lg], acc, 0, 0, 0);
                acc = __builtin_amdgcn_mfma_f32_16x16x32_fp8_fp8((long)wrow[(7<<6)|lane], (long)c_f8[(28)|lg], acc, 0, 0, 0);
                if (wr0) {
                    int row = (rt2 << 4) + (lg << 2);
                    float4 xbv = *(float4*)(xb + row);
                    float4 r;
                    r.x = fmaxf(xbv.x + acc[0] * INV512, 0.f);
                    r.y = fmaxf(xbv.y + acc[1] * INV512, 0.f);
                    r.z = fmaxf(xbv.z + acc[2] * INV512, 0.f);
                    r.w = fmaxf(xbv.w + acc[3] * INV512, 0.f);
                    *(float4*)(xv + row) = r;
                }
            }
        }
        __syncthreads();
        if (t < 64) {  // pack x -> fp8
            int pk = 0;
            pk = __builtin_amdgcn_cvt_pk_fp8_f32(xv[4*t]*VSCL,   xv[4*t+1]*VSCL, pk, false);
            pk = __builtin_amdgcn_cvt_pk_fp8_f32(xv[4*t+2]*VSCL, xv[4*t+3]*VSCL, pk, true);
            ((unsigned int*)x_f8)[t] = (unsigned int)pk;
        }
        __syncthreads();
        // D5: gi = Wih.x ; gh = Whh.h  via MFMA (raw = 512x)
        {
            f32x4 ai = {0.f, 0.f, 0.f, 0.f}; f32x4 ah = {0.f, 0.f, 0.f, 0.f};
            MFMA_ROW(aI0, x_f8, ai) MFMA_ROW(aH0, h_f8, ah)
            if (wr0) { int row = (w << 6) +  0 + (lg << 2);
                *(f32x4*)(gi2 + row) = ai; *(f32x4*)(gg + row) = ah; }
        }
        {
            f32x4 ai = {0.f, 0.f, 0.f, 0.f}; f32x4 ah = {0.f, 0.f, 0.f, 0.f};
            MFMA_ROW(aI1, x_f8, ai) MFMA_ROW(aH1, h_f8, ah)
            if (wr0) { int row = (w << 6) + 16 + (lg << 2);
                *(f32x4*)(gi2 + row) = ai; *(f32x4*)(gg + row) = ah; }
        }
        {
            f32x4 ai = {0.f, 0.f, 0.f, 0.f}; f32x4 ah = {0.f, 0.f, 0.f, 0.f};
            MFMA_ROW(aI2, x_f8, ai) MFMA_ROW(aH2, h_f8, ah)
            if (wr0) { int row = (w << 6) + 32 + (lg << 2);
                *(f32x4*)(gi2 + row) = ai; *(f32x4*)(gg + row) = ah; }
        }
        {
            f32x4 ai = {0.f, 0.f, 0.f, 0.f}; f32x4 ah = {0.f, 0.f, 0.f, 0.f};
            MFMA_ROW(aI3, x_f8, ai) MFMA_ROW(aH3, h_f8, ah)
            if (wr0) { int row = (w << 6) + 48 + (lg << 2);
                *(f32x4*)(gi2 + row) = ai; *(f32x4*)(gg + row) = ah; }
        }
        __syncthreads();
        // D6: GRU elementwise update
        if (t < HH) {
            float r = sigmf((gi2[t] + gg[t]) * INV512 + bi0 + bh0);
            float z = sigmf((gi2[HH + t] + gg[HH + t]) * INV512 + bi1 + bh1);
            float n = tanhf(gi2[2 * HH + t] * INV512 + bi2 +
                            r * (gg[2 * HH + t] * INV512 + bh2));
            h[t] = (1.f - z) * n + z * h[t];
        }
        __syncthreads();
        // D7: p_tok = sigmoid(h . W_out[tok] + b_out[tok])  (fp32, wave 0)
        if (t < 64) {
            float4 hv = ((const float4*)h)[t];
            float a = wo.x * hv.x + wo.y * hv.y + wo.z * hv.z + wo.w * hv.w;
            #pragma unroll
            for (int off = 32; off; off >>= 1) a += __shfl_xor(a, off);
            if (t == 0) out[1 + b * TT + di] = sigmf(a + bov);
        }
        // next iteration's first barrier protects h_f8 repack
    }
}

// ---------------------------------------------------------------------------
// Kernel C: BCE loss over the 2048 gathered probabilities -> out[0]
// ---------------------------------------------------------------------------
__global__ __launch_bounds__(256) void loss_kernel(const int* __restrict__ ts,
                                                   float* __restrict__ out)
{
    __shared__ float red[4];
    const int t = threadIdx.x;
    const float tv = (float)ts[0];
    float sum = 0.f;
    for (int i = t; i < BB * TT; i += 256) {
        float p = out[1 + i];
        float lp  = fmaxf(__logf(p), -100.f);
        float l1p = fmaxf(__logf(1.f - p), -100.f);
        sum += tv * lp + (1.f - tv) * l1p;
    }
    #pragma unroll
    for (int off = 32; off; off >>= 1) sum += __shfl_xor(sum, off);
    if ((t & 63) == 0) red[t >> 6] = sum;
    __syncthreads();
    if (t == 0) out[0] = -(red[0] + red[1] + red[2] + red[3]) / (float)(BB * TT);
}

// ---------------------------------------------------------------------------
extern "C" void kernel_launch(void* const* d_in, const int* in_sizes, int n_in,
                              void* d_out, int out_size, void* d_ws, size_t ws_size,
                              hipStream_t stream)
{
    const int*   ctx     = (const int*)d_in[0];
    const int*   inp     = (const int*)d_in[1];
    const int*   ts      = (const int*)d_in[2];
    const float* enc_emb = (const float*)d_in[3];
    const float* eWih    = (const float*)d_in[4];
    const float* eWhh    = (const float*)d_in[5];
    const float* ebih    = (const float*)d_in[6];
    const float* ebhh    = (const float*)d_in[7];
    const float* demb    = (const float*)d_in[8];
    const float* Wc      = (const float*)d_in[9];
    const float* bc      = (const float*)d_in[10];
    const float* dWih    = (const float*)d_in[11];
    const float* dWhh    = (const float*)d_in[12];
    const float* dbih    = (const float*)d_in[13];
    const float* dbhh    = (const float*)d_in[14];
    const float* Wo      = (const float*)d_in[15];
    const float* bo      = (const float*)d_in[16];
    float* out = (float*)d_out;
    float* GI  = (float*)d_ws;   // 64*32*768 f32 = 6.29 MB (proven footprint)

    hipLaunchKernelGGL(gi_pre_kernel, dim3(SC * 24), dim3(256), 0, stream,
                       ctx, enc_emb, eWih, ebih, GI);
    hipLaunchKernelGGL(seq_kernel, dim3(BB), dim3(G3), 0, stream,
                       inp, GI, eWhh, ebhh, demb, Wc, bc,
                       dWih, dWhh, dbih, dbhh, Wo, bo, out);
    hipLaunchKernelGGL(loss_kernel, dim3(1), dim3(256), 0, stream, ts, out);
}

// Round 6
// 1025.882 us; speedup vs baseline: 1.0337x; 1.0337x over previous
//
#include <hip/hip_runtime.h>
#include <hip/hip_bf16.h>
#include <cstdint>
#include <cstddef>

// Dims (fixed by the reference)
#define BB 32     // batch
#define SC 64     // context length
#define TT 64     // decode steps
#define HH 256    // hidden
#define G3 768    // 3*H
#define VV 32000  // vocab

#define WSCL 16.f     // weight scale before fp8 quantization
#define VSCL 32.f     // vector (h/x/ctx) scale before fp8 quantization
#define INV512 (1.f / (WSCL * VSCL))

typedef float f32x4 __attribute__((ext_vector_type(4)));

__device__ __forceinline__ float sigmf(float x) { return 1.f / (1.f + __expf(-x)); }

// pack 8 consecutive fp32 (scaled by WSCL) into one fp8x8 fragment word
__device__ __forceinline__ unsigned long long pack_row8(const float* __restrict__ p) {
    int lo = 0, hi = 0;
    lo = __builtin_amdgcn_cvt_pk_fp8_f32(p[0] * WSCL, p[1] * WSCL, lo, false);
    lo = __builtin_amdgcn_cvt_pk_fp8_f32(p[2] * WSCL, p[3] * WSCL, lo, true);
    hi = __builtin_amdgcn_cvt_pk_fp8_f32(p[4] * WSCL, p[5] * WSCL, hi, false);
    hi = __builtin_amdgcn_cvt_pk_fp8_f32(p[6] * WSCL, p[7] * WSCL, hi, true);
    return ((unsigned long long)(unsigned int)hi << 32) | (unsigned long long)(unsigned int)lo;
}

// Declare one 16-row x 256-K fragment group (8 named longs) for row-tile `nm`,
// then PIN them into AGPRs so the allocator cannot spill/remat them.
#define DECL_ROW(nm, rowptr)                                 \
    const float* nm##_p = (rowptr) + (lg << 3);              \
    long nm##0 = (long)pack_row8(nm##_p + 0);                \
    long nm##1 = (long)pack_row8(nm##_p + 32);               \
    long nm##2 = (long)pack_row8(nm##_p + 64);               \
    long nm##3 = (long)pack_row8(nm##_p + 96);               \
    long nm##4 = (long)pack_row8(nm##_p + 128);              \
    long nm##5 = (long)pack_row8(nm##_p + 160);              \
    long nm##6 = (long)pack_row8(nm##_p + 192);              \
    long nm##7 = (long)pack_row8(nm##_p + 224);              \
    asm("" : "+a"(nm##0), "+a"(nm##1), "+a"(nm##2), "+a"(nm##3), \
             "+a"(nm##4), "+a"(nm##5), "+a"(nm##6), "+a"(nm##7));

// Accumulate one row-tile x full-K (8 MFMAs) against B-vector fragments in LDS.
#define MFMA_ROW(nm, bsrc, acc)                                                              \
    acc = __builtin_amdgcn_mfma_f32_16x16x32_fp8_fp8(nm##0, (long)(bsrc)[( 0) | lg], acc, 0, 0, 0); \
    acc = __builtin_amdgcn_mfma_f32_16x16x32_fp8_fp8(nm##1, (long)(bsrc)[( 4) | lg], acc, 0, 0, 0); \
    acc = __builtin_amdgcn_mfma_f32_16x16x32_fp8_fp8(nm##2, (long)(bsrc)[( 8) | lg], acc, 0, 0, 0); \
    acc = __builtin_amdgcn_mfma_f32_16x16x32_fp8_fp8(nm##3, (long)(bsrc)[(12) | lg], acc, 0, 0, 0); \
    acc = __builtin_amdgcn_mfma_f32_16x16x32_fp8_fp8(nm##4, (long)(bsrc)[(16) | lg], acc, 0, 0, 0); \
    acc = __builtin_amdgcn_mfma_f32_16x16x32_fp8_fp8(nm##5, (long)(bsrc)[(20) | lg], acc, 0, 0, 0); \
    acc = __builtin_amdgcn_mfma_f32_16x16x32_fp8_fp8(nm##6, (long)(bsrc)[(24) | lg], acc, 0, 0, 0); \
    acc = __builtin_amdgcn_mfma_f32_16x16x32_fp8_fp8(nm##7, (long)(bsrc)[(28) | lg], acc, 0, 0, 0);

// ---------------------------------------------------------------------------
// Kernel A: precompute GI_enc[s][b][g] = enc_emb[ctx[b][s]] . enc_Wih[g] + bih[g]
// (fp32, exact)
// ---------------------------------------------------------------------------
__global__ __launch_bounds__(256) void gi_pre_kernel(
    const int* __restrict__ ctx, const float* __restrict__ emb,
    const float* __restrict__ Wih, const float* __restrict__ bih,
    float* __restrict__ GI)
{
    __shared__ float4 xl[BB][HH / 4];
    __shared__ int tokl[BB];
    const int bid = blockIdx.x;
    const int s  = bid / 24;
    const int g0 = (bid % 24) * 32;
    const int t  = threadIdx.x;

    if (t < BB) tokl[t] = ctx[t * SC + s];
    __syncthreads();
    #pragma unroll
    for (int i = 0; i < 8; ++i) {
        int f = t + 256 * i;
        int b = f >> 6, c = f & 63;
        xl[b][c] = ((const float4*)(emb + (size_t)tokl[b] * HH))[c];
    }
    __syncthreads();

    const int gl = t & 31, bq = t >> 5;
    const float4* wr = (const float4*)(Wih + (size_t)(g0 + gl) * HH);
    float a0 = 0.f, a1 = 0.f, a2 = 0.f, a3 = 0.f;
    #pragma unroll 4
    for (int k = 0; k < HH / 4; ++k) {
        float4 w  = wr[k];
        float4 x0 = xl[bq * 4 + 0][k];
        float4 x1 = xl[bq * 4 + 1][k];
        float4 x2 = xl[bq * 4 + 2][k];
        float4 x3 = xl[bq * 4 + 3][k];
        a0 += w.x * x0.x + w.y * x0.y + w.z * x0.z + w.w * x0.w;
        a1 += w.x * x1.x + w.y * x1.y + w.z * x1.z + w.w * x1.w;
        a2 += w.x * x2.x + w.y * x2.y + w.z * x2.z + w.w * x2.w;
        a3 += w.x * x3.x + w.y * x3.y + w.z * x3.z + w.w * x3.w;
    }
    const float bv = bih[g0 + gl];
    GI[(size_t)(s * BB + bq * 4 + 0) * G3 + g0 + gl] = a0 + bv;
    GI[(size_t)(s * BB + bq * 4 + 1) * G3 + g0 + gl] = a1 + bv;
    GI[(size_t)(s * BB + bq * 4 + 2) * G3 + g0 + gl] = a2 + bv;
    GI[(size_t)(s * BB + bq * 4 + 3) * G3 + g0 + gl] = a3 + bv;
}

// ---------------------------------------------------------------------------
// Kernel B: full recurrence, one block per batch element (32 blocks x 768 thr).
// Gate matvecs via fp8 MFMA; weight fragments pinned in AGPRs.
// ---------------------------------------------------------------------------
__global__ __launch_bounds__(768)
__attribute__((amdgpu_waves_per_eu(1, 3)))
void seq_kernel(
    const int*   __restrict__ inp,
    const float* __restrict__ GI,
    const float* __restrict__ eWhh, const float* __restrict__ ebhh,
    const float* __restrict__ demb,
    const float* __restrict__ Wc,   const float* __restrict__ bc,
    const float* __restrict__ dWih, const float* __restrict__ dWhh,
    const float* __restrict__ dbih, const float* __restrict__ dbhh,
    const float* __restrict__ Wo,   const float* __restrict__ bo,
    float* __restrict__ out)
{
    __shared__ float eo[SC][HH];                       // 64 KB encoder outputs
    __shared__ unsigned long long wc2l[8192];          // 64 KB Wc2 fp8 frags
    __shared__ float h[HH];
    __shared__ float gg[G3];                           // gh raw (x512)
    __shared__ float gi2[G3];                          // gi raw (x512)
    __shared__ float sc[SC];
    __shared__ float ctxv[HH];
    __shared__ float xv[HH];
    __shared__ float xb[HH];
    __shared__ unsigned long long h_f8[32];            // h  * VSCL, fp8
    __shared__ unsigned long long c_f8[32];            // ctx* VSCL, fp8
    __shared__ unsigned long long x_f8[32];            // x  * VSCL, fp8
    __shared__ int tokl[TT];

    const int b    = blockIdx.x;
    const int t    = threadIdx.x;
    const int lane = t & 63;
    const int w    = t >> 6;          // wave id 0..11
    const int lg   = lane >> 4;       // k-group 0..3
    const int rr   = lane & 15;       // row within 16-row tile
    const bool wr0 = (rr == 0);

    if (t < TT) tokl[t] = inp[b * TT + t];

    // stage Wc2 (right half of W_comb) as fp8 fragments into LDS
    for (int i = t; i < 8192; i += 768) {
        const int lf = i & 63, kt = (i >> 6) & 7, rt2 = i >> 9;
        const float* p = Wc + (size_t)(rt2 * 16 + (lf & 15)) * (2 * HH)
                       + HH + kt * 32 + (lf >> 4) * 8;
        wc2l[i] = pack_row8(p);
    }

    // per-thread gate biases (t<256)
    float bi0 = 0.f, bi1 = 0.f, bi2 = 0.f, bh0 = 0.f, bh1 = 0.f, bh2 = 0.f;
    float eb0 = 0.f, eb1 = 0.f, eb2 = 0.f;
    if (t < HH) {
        bi0 = dbih[t]; bi1 = dbih[HH + t]; bi2 = dbih[2 * HH + t];
        bh0 = dbhh[t]; bh1 = dbhh[HH + t]; bh2 = dbhh[2 * HH + t];
        eb0 = ebhh[t]; eb1 = ebhh[HH + t]; eb2 = ebhh[2 * HH + t];
        // init h = 0 and xb[j] = b_comb[j] + emb_sos . W_comb[j, 0:256]  (fp32)
        h[t] = 0.f;
        float a = bc[t];
        const float4* wrp = (const float4*)(Wc + (size_t)t * (2 * HH));
        const float4* es  = (const float4*)(demb + HH);     // SOS_INDEX = 1
        #pragma unroll
        for (int k = 0; k < HH / 4; ++k) {
            float4 wv = wrp[k], e = es[k];
            a += wv.x * e.x + wv.y * e.y + wv.z * e.z + wv.w * e.w;
        }
        xb[t] = a;
    }

    // ================= encoder =================
    {
        // quantize this wave's eWhh rows into AGPR-pinned fragments
        DECL_ROW(aE0, eWhh + (size_t)((w << 6) +  0 + rr) * HH)
        DECL_ROW(aE1, eWhh + (size_t)((w << 6) + 16 + rr) * HH)
        DECL_ROW(aE2, eWhh + (size_t)((w << 6) + 32 + rr) * HH)
        DECL_ROW(aE3, eWhh + (size_t)((w << 6) + 48 + rr) * HH)

        // GI double-buffer: preload s = 0
        float g0 = 0.f, g1 = 0.f, g2 = 0.f;
        if (t < HH) {
            const float* gp = GI + (size_t)b * G3;
            g0 = gp[t]; g1 = gp[HH + t]; g2 = gp[2 * HH + t];
        }
        __syncthreads();

        for (int s = 0; s < SC; ++s) {
            float gn0 = 0.f, gn1 = 0.f, gn2 = 0.f;
            if (t < HH && s + 1 < SC) {
                const float* gp = GI + (size_t)((s + 1) * BB + b) * G3;
                gn0 = gp[t]; gn1 = gp[HH + t]; gn2 = gp[2 * HH + t];
            }
            if (t < 64) {   // pack h -> fp8 (x VSCL)
                int pk = 0;
                pk = __builtin_amdgcn_cvt_pk_fp8_f32(h[4*t]*VSCL,   h[4*t+1]*VSCL, pk, false);
                pk = __builtin_amdgcn_cvt_pk_fp8_f32(h[4*t+2]*VSCL, h[4*t+3]*VSCL, pk, true);
                ((unsigned int*)h_f8)[t] = (unsigned int)pk;
            }
            __syncthreads();
            // gh = Whh.h via MFMA (raw = 512x)
            {
                f32x4 acc = {0.f, 0.f, 0.f, 0.f};
                MFMA_ROW(aE0, h_f8, acc)
                if (wr0) *(f32x4*)(gg + (w << 6) +  0 + (lg << 2)) = acc;
            }
            {
                f32x4 acc = {0.f, 0.f, 0.f, 0.f};
                MFMA_ROW(aE1, h_f8, acc)
                if (wr0) *(f32x4*)(gg + (w << 6) + 16 + (lg << 2)) = acc;
            }
            {
                f32x4 acc = {0.f, 0.f, 0.f, 0.f};
                MFMA_ROW(aE2, h_f8, acc)
                if (wr0) *(f32x4*)(gg + (w << 6) + 32 + (lg << 2)) = acc;
            }
            {
                f32x4 acc = {0.f, 0.f, 0.f, 0.f};
                MFMA_ROW(aE3, h_f8, acc)
                if (wr0) *(f32x4*)(gg + (w << 6) + 48 + (lg << 2)) = acc;
            }
            __syncthreads();
            if (t < HH) {
                float r = sigmf(g0 + gg[t] * INV512 + eb0);
                float z = sigmf(g1 + gg[HH + t] * INV512 + eb1);
                float n = tanhf(g2 + r * (gg[2 * HH + t] * INV512 + eb2));
                float hn = (1.f - z) * n + z * h[t];
                h[t] = hn;
                eo[s][t] = hn;
            }
            g0 = gn0; g1 = gn1; g2 = gn2;
            __syncthreads();
        }
    }

    // ================= decoder =================
    // quantize this wave's dWih / dWhh rows into AGPR-pinned fragments
    DECL_ROW(aI0, dWih + (size_t)((w << 6) +  0 + rr) * HH)
    DECL_ROW(aI1, dWih + (size_t)((w << 6) + 16 + rr) * HH)
    DECL_ROW(aI2, dWih + (size_t)((w << 6) + 32 + rr) * HH)
    DECL_ROW(aI3, dWih + (size_t)((w << 6) + 48 + rr) * HH)
    DECL_ROW(aH0, dWhh + (size_t)((w << 6) +  0 + rr) * HH)
    DECL_ROW(aH1, dWhh + (size_t)((w << 6) + 16 + rr) * HH)
    DECL_ROW(aH2, dWhh + (size_t)((w << 6) + 32 + rr) * HH)
    DECL_ROW(aH3, dWhh + (size_t)((w << 6) + 48 + rr) * HH)

    for (int di = 0; di < TT; ++di) {
        // prefetch W_out[tok] row + b_out[tok] (consumed in D7)
        float4 wo = {0.f, 0.f, 0.f, 0.f};
        float bov = 0.f;
        if (t < 64) {
            const int tok = tokl[di];
            wo  = ((const float4*)(Wo + (size_t)tok * HH))[t];
            bov = bo[tok];
            // pack h -> fp8
            int pk = 0;
            pk = __builtin_amdgcn_cvt_pk_fp8_f32(h[4*t]*VSCL,   h[4*t+1]*VSCL, pk, false);
            pk = __builtin_amdgcn_cvt_pk_fp8_f32(h[4*t+2]*VSCL, h[4*t+3]*VSCL, pk, true);
            ((unsigned int*)h_f8)[t] = (unsigned int)pk;
        }
        __syncthreads();
        // D1: attention scores[s] = eo[s] . h  (fp32, 4 lanes per s, staggered)
        if (t < 256) {
            const int s = t >> 2, c = t & 3;
            float acc = 0.f;
            #pragma unroll 4
            for (int k = 0; k < 64; ++k) {
                int kk = ((k + s + c * 16) & 63) + c * 64;
                acc += eo[s][kk] * h[kk];
            }
            acc += __shfl_xor(acc, 1);
            acc += __shfl_xor(acc, 2);
            if (c == 0) sc[s] = acc;
        }
        __syncthreads();
        // D2: softmax over 64 scores
        if (t < 64) {
            float v = sc[t];
            float m = v;
            #pragma unroll
            for (int off = 32; off; off >>= 1) m = fmaxf(m, __shfl_xor(m, off));
            float e = __expf(v - m);
            float su = e;
            #pragma unroll
            for (int off = 32; off; off >>= 1) su += __shfl_xor(su, off);
            sc[t] = e / su;
        }
        __syncthreads();
        // D3: ctx[j] = sum_s attn[s] * eo[s][j]
        if (t < HH) {
            float a = 0.f;
            #pragma unroll 4
            for (int s = 0; s < SC; ++s) a += sc[s] * eo[s][t];
            ctxv[t] = a;
        }
        __syncthreads();
        if (t < 64) {  // pack ctx -> fp8
            int pk = 0;
            pk = __builtin_amdgcn_cvt_pk_fp8_f32(ctxv[4*t]*VSCL,   ctxv[4*t+1]*VSCL, pk, false);
            pk = __builtin_amdgcn_cvt_pk_fp8_f32(ctxv[4*t+2]*VSCL, ctxv[4*t+3]*VSCL, pk, true);
            ((unsigned int*)c_f8)[t] = (unsigned int)pk;
        }
        __syncthreads();
        // D4: x = relu(xb + Wc2.ctx) via MFMA on waves 0..7 (2 row-tiles each)
        if (w < 8) {
            #pragma unroll
            for (int i = 0; i < 2; ++i) {
                const int rt2 = (w << 1) + i;        // 0..15
                f32x4 acc = {0.f, 0.f, 0.f, 0.f};
                const unsigned long long* wrow = wc2l + (rt2 << 9);
                acc = __builtin_amdgcn_mfma_f32_16x16x32_fp8_fp8((long)wrow[(0<<6)|lane], (long)c_f8[( 0)|lg], acc, 0, 0, 0);
                acc = __builtin_amdgcn_mfma_f32_16x16x32_fp8_fp8((long)wrow[(1<<6)|lane], (long)c_f8[( 4)|lg], acc, 0, 0, 0);
                acc = __builtin_amdgcn_mfma_f32_16x16x32_fp8_fp8((long)wrow[(2<<6)|lane], (long)c_f8[( 8)|lg], acc, 0, 0, 0);
                acc = __builtin_amdgcn_mfma_f32_16x16x32_fp8_fp8((long)wrow[(3<<6)|lane], (long)c_f8[(12)|lg], acc, 0, 0, 0);
                acc = __builtin_amdgcn_mfma_f32_16x16x32_fp8_fp8((long)wrow[(4<<6)|lane], (long)c_f8[(16)|lg], acc, 0, 0, 0);
                acc = __builtin_amdgcn_mfma_f32_16x16x32_fp8_fp8((long)wrow[(5<<6)|lane], (long)c_f8[(20)|lg], acc, 0, 0, 0);
                acc = __builtin_amdgcn_mfma_f32_16x16x32_fp8_fp8((long)wrow[(6<<6)|lane], (long)c_f8[(24)|lg], acc, 0, 0, 0);
                acc = __builtin_amdgcn_mfma_f32_16x16x32_fp8_fp8((long)wrow[(7<<6)|lane], (long)c_f8[(28)|lg], acc, 0, 0, 0);
                if (wr0) {
                    int row = (rt2 << 4) + (lg << 2);
                    float4 xbv = *(float4*)(xb + row);
                    float4 r;
                    r.x = fmaxf(xbv.x + acc[0] * INV512, 0.f);
                    r.y = fmaxf(xbv.y + acc[1] * INV512, 0.f);
                    r.z = fmaxf(xbv.z + acc[2] * INV512, 0.f);
                    r.w = fmaxf(xbv.w + acc[3] * INV512, 0.f);
                    *(float4*)(xv + row) = r;
                }
            }
        }
        __syncthreads();
        if (t < 64) {  // pack x -> fp8
            int pk = 0;
            pk = __builtin_amdgcn_cvt_pk_fp8_f32(xv[4*t]*VSCL,   xv[4*t+1]*VSCL, pk, false);
            pk = __builtin_amdgcn_cvt_pk_fp8_f32(xv[4*t+2]*VSCL, xv[4*t+3]*VSCL, pk, true);
            ((unsigned int*)x_f8)[t] = (unsigned int)pk;
        }
        __syncthreads();
        // D5: gi = Wih.x ; gh = Whh.h  via MFMA (raw = 512x)
        {
            f32x4 ai = {0.f, 0.f, 0.f, 0.f}; f32x4 ah = {0.f, 0.f, 0.f, 0.f};
            MFMA_ROW(aI0, x_f8, ai) MFMA_ROW(aH0, h_f8, ah)
            if (wr0) { int row = (w << 6) +  0 + (lg << 2);
                *(f32x4*)(gi2 + row) = ai; *(f32x4*)(gg + row) = ah; }
        }
        {
            f32x4 ai = {0.f, 0.f, 0.f, 0.f}; f32x4 ah = {0.f, 0.f, 0.f, 0.f};
            MFMA_ROW(aI1, x_f8, ai) MFMA_ROW(aH1, h_f8, ah)
            if (wr0) { int row = (w << 6) + 16 + (lg << 2);
                *(f32x4*)(gi2 + row) = ai; *(f32x4*)(gg + row) = ah; }
        }
        {
            f32x4 ai = {0.f, 0.f, 0.f, 0.f}; f32x4 ah = {0.f, 0.f, 0.f, 0.f};
            MFMA_ROW(aI2, x_f8, ai) MFMA_ROW(aH2, h_f8, ah)
            if (wr0) { int row = (w << 6) + 32 + (lg << 2);
                *(f32x4*)(gi2 + row) = ai; *(f32x4*)(gg + row) = ah; }
        }
        {
            f32x4 ai = {0.f, 0.f, 0.f, 0.f}; f32x4 ah = {0.f, 0.f, 0.f, 0.f};
            MFMA_ROW(aI3, x_f8, ai) MFMA_ROW(aH3, h_f8, ah)
            if (wr0) { int row = (w << 6) + 48 + (lg << 2);
                *(f32x4*)(gi2 + row) = ai; *(f32x4*)(gg + row) = ah; }
        }
        __syncthreads();
        // D6: GRU elementwise update
        if (t < HH) {
            float r = sigmf((gi2[t] + gg[t]) * INV512 + bi0 + bh0);
            float z = sigmf((gi2[HH + t] + gg[HH + t]) * INV512 + bi1 + bh1);
            float n = tanhf(gi2[2 * HH + t] * INV512 + bi2 +
                            r * (gg[2 * HH + t] * INV512 + bh2));
            h[t] = (1.f - z) * n + z * h[t];
        }
        __syncthreads();
        // D7: p_tok = sigmoid(h . W_out[tok] + b_out[tok])  (fp32, wave 0)
        if (t < 64) {
            float4 hv = ((const float4*)h)[t];
            float a = wo.x * hv.x + wo.y * hv.y + wo.z * hv.z + wo.w * hv.w;
            #pragma unroll
            for (int off = 32; off; off >>= 1) a += __shfl_xor(a, off);
            if (t == 0) out[1 + b * TT + di] = sigmf(a + bov);
        }
        // next iteration's first barrier protects h_f8 repack
    }
}

// ---------------------------------------------------------------------------
// Kernel C: BCE loss over the 2048 gathered probabilities -> out[0]
// ---------------------------------------------------------------------------
__global__ __launch_bounds__(256) void loss_kernel(const int* __restrict__ ts,
                                                   float* __restrict__ out)
{
    __shared__ float red[4];
    const int t = threadIdx.x;
    const float tv = (float)ts[0];
    float sum = 0.f;
    for (int i = t; i < BB * TT; i += 256) {
        float p = out[1 + i];
        float lp  = fmaxf(__logf(p), -100.f);
        float l1p = fmaxf(__logf(1.f - p), -100.f);
        sum += tv * lp + (1.f - tv) * l1p;
    }
    #pragma unroll
    for (int off = 32; off; off >>= 1) sum += __shfl_xor(sum, off);
    if ((t & 63) == 0) red[t >> 6] = sum;
    __syncthreads();
    if (t == 0) out[0] = -(red[0] + red[1] + red[2] + red[3]) / (float)(BB * TT);
}

// ---------------------------------------------------------------------------
extern "C" void kernel_launch(void* const* d_in, const int* in_sizes, int n_in,
                              void* d_out, int out_size, void* d_ws, size_t ws_size,
                              hipStream_t stream)
{
    const int*   ctx     = (const int*)d_in[0];
    const int*   inp     = (const int*)d_in[1];
    const int*   ts      = (const int*)d_in[2];
    const float* enc_emb = (const float*)d_in[3];
    const float* eWih    = (const float*)d_in[4];
    const float* eWhh    = (const float*)d_in[5];
    const float* ebih    = (const float*)d_in[6];
    const float* ebhh    = (const float*)d_in[7];
    const float* demb    = (const float*)d_in[8];
    const float* Wc      = (const float*)d_in[9];
    const float* bc      = (const float*)d_in[10];
    const float* dWih    = (const float*)d_in[11];
    const float* dWhh    = (const float*)d_in[12];
    const float* dbih    = (const float*)d_in[13];
    const float* dbhh    = (const float*)d_in[14];
    const float* Wo      = (const float*)d_in[15];
    const float* bo      = (const float*)d_in[16];
    float* out = (float*)d_out;
    float* GI  = (float*)d_ws;   // 64*32*768 f32 = 6.29 MB (proven footprint)

    hipLaunchKernelGGL(gi_pre_kernel, dim3(SC * 24), dim3(256), 0, stream,
                       ctx, enc_emb, eWih, ebih, GI);
    hipLaunchKernelGGL(seq_kernel, dim3(BB), dim3(G3), 0, stream,
                       inp, GI, eWhh, ebhh, demb, Wc, bc,
                       dWih, dWhh, dbih, dbhh, Wo, bo, out);
    hipLaunchKernelGGL(loss_kernel, dim3(1), dim3(256), 0, stream, ts, out);
}

// Round 8
// 668.888 us; speedup vs baseline: 1.5854x; 1.5337x over previous
//
#include <hip/hip_runtime.h>
#include <hip/hip_bf16.h>
#include <cstdint>
#include <cstddef>

// Dims (fixed by the reference)
#define BB 32     // batch
#define SC 64     // context length
#define TT 64     // decode steps
#define HH 256    // hidden
#define G3 768    // 3*H
#define VV 32000  // vocab

// scales: weights x16, h/x/ctx x32, attn x64
#define WSCL 16.f
#define VSCL 32.f
#define ASCL 64.f
#define INV512  (1.f / (16.f * 32.f))
#define INV1024 (1.f / (32.f * 32.f))
#define CPACK   (32.f / 2048.f)     // ctx_raw(32*64) -> byte(x32)

typedef float f32x4 __attribute__((ext_vector_type(4)));
#define MFMA8(a, b, c) __builtin_amdgcn_mfma_f32_16x16x32_fp8_fp8((a), (b), (c), 0, 0, 0)
#define CVTPK __builtin_amdgcn_cvt_pk_fp8_f32

__device__ __forceinline__ float sigmf(float x) { return 1.f / (1.f + __expf(-x)); }

// pack 8 consecutive fp32 (scaled by WSCL) into one fp8x8 fragment word
__device__ __forceinline__ unsigned long long pack_row8(const float* __restrict__ p) {
    int lo = 0, hi = 0;
    lo = CVTPK(p[0] * WSCL, p[1] * WSCL, lo, false);
    lo = CVTPK(p[2] * WSCL, p[3] * WSCL, lo, true);
    hi = CVTPK(p[4] * WSCL, p[5] * WSCL, hi, false);
    hi = CVTPK(p[6] * WSCL, p[7] * WSCL, hi, true);
    return ((unsigned long long)(unsigned int)hi << 32) | (unsigned long long)(unsigned int)lo;
}

// one 16-row x K=256 A-fragment group (8 named longs), AGPR-pinned
#define DECL_ROW(nm, rowptr)                                 \
    const float* nm##_p = (rowptr) + (lg << 3);              \
    long nm##0 = (long)pack_row8(nm##_p + 0);                \
    long nm##1 = (long)pack_row8(nm##_p + 32);               \
    long nm##2 = (long)pack_row8(nm##_p + 64);               \
    long nm##3 = (long)pack_row8(nm##_p + 96);               \
    long nm##4 = (long)pack_row8(nm##_p + 128);              \
    long nm##5 = (long)pack_row8(nm##_p + 160);              \
    long nm##6 = (long)pack_row8(nm##_p + 192);              \
    long nm##7 = (long)pack_row8(nm##_p + 224);              \
    asm("" : "+a"(nm##0), "+a"(nm##1), "+a"(nm##2), "+a"(nm##3), \
             "+a"(nm##4), "+a"(nm##5), "+a"(nm##6), "+a"(nm##7));

// 6 tiles per wave (96 rows), rows RB..RB+95
#define DECL6(pre, W)                                            \
    DECL_ROW(pre##0, (W) + (size_t)(RB +  0 + rr) * HH)          \
    DECL_ROW(pre##1, (W) + (size_t)(RB + 16 + rr) * HH)          \
    DECL_ROW(pre##2, (W) + (size_t)(RB + 32 + rr) * HH)          \
    DECL_ROW(pre##3, (W) + (size_t)(RB + 48 + rr) * HH)          \
    DECL_ROW(pre##4, (W) + (size_t)(RB + 64 + rr) * HH)          \
    DECL_ROW(pre##5, (W) + (size_t)(RB + 80 + rr) * HH)

// hoist the 8 B-operand words for this lane's k-group
#define LDB(src) \
    const long bq0=(long)(src)[lg],      bq1=(long)(src)[4|lg],  \
               bq2=(long)(src)[8|lg],    bq3=(long)(src)[12|lg], \
               bq4=(long)(src)[16|lg],   bq5=(long)(src)[20|lg], \
               bq6=(long)(src)[24|lg],   bq7=(long)(src)[28|lg];

#define MROW(nm, acc)                                            \
    acc = MFMA8(nm##0, bq0, acc); acc = MFMA8(nm##1, bq1, acc);  \
    acc = MFMA8(nm##2, bq2, acc); acc = MFMA8(nm##3, bq3, acc);  \
    acc = MFMA8(nm##4, bq4, acc); acc = MFMA8(nm##5, bq5, acc);  \
    acc = MFMA8(nm##6, bq6, acc); acc = MFMA8(nm##7, bq7, acc);

#define DO6(pre, dst)                                                                   \
    { f32x4 acc={0,0,0,0}; MROW(pre##0,acc) if(wr0)*(f32x4*)((dst)+RB+ 0+(lg<<2))=acc; }\
    { f32x4 acc={0,0,0,0}; MROW(pre##1,acc) if(wr0)*(f32x4*)((dst)+RB+16+(lg<<2))=acc; }\
    { f32x4 acc={0,0,0,0}; MROW(pre##2,acc) if(wr0)*(f32x4*)((dst)+RB+32+(lg<<2))=acc; }\
    { f32x4 acc={0,0,0,0}; MROW(pre##3,acc) if(wr0)*(f32x4*)((dst)+RB+48+(lg<<2))=acc; }\
    { f32x4 acc={0,0,0,0}; MROW(pre##4,acc) if(wr0)*(f32x4*)((dst)+RB+64+(lg<<2))=acc; }\
    { f32x4 acc={0,0,0,0}; MROW(pre##5,acc) if(wr0)*(f32x4*)((dst)+RB+80+(lg<<2))=acc; }

// ---------------------------------------------------------------------------
// Kernel A: GI_enc[s][b][g] = enc_emb[ctx[b][s]] . enc_Wih[g] + bih[g] (fp32)
// ---------------------------------------------------------------------------
__global__ __launch_bounds__(256) void gi_pre_kernel(
    const int* __restrict__ ctx, const float* __restrict__ emb,
    const float* __restrict__ Wih, const float* __restrict__ bih,
    float* __restrict__ GI)
{
    __shared__ float4 xl[BB][HH / 4];
    __shared__ int tokl[BB];
    const int bid = blockIdx.x;
    const int s  = bid / 24;
    const int g0 = (bid % 24) * 32;
    const int t  = threadIdx.x;

    if (t < BB) tokl[t] = ctx[t * SC + s];
    __syncthreads();
    #pragma unroll
    for (int i = 0; i < 8; ++i) {
        int f = t + 256 * i;
        int b = f >> 6, c = f & 63;
        xl[b][c] = ((const float4*)(emb + (size_t)tokl[b] * HH))[c];
    }
    __syncthreads();

    const int gl = t & 31, bq = t >> 5;
    const float4* wr = (const float4*)(Wih + (size_t)(g0 + gl) * HH);
    float a0 = 0.f, a1 = 0.f, a2 = 0.f, a3 = 0.f;
    #pragma unroll 4
    for (int k = 0; k < HH / 4; ++k) {
        float4 w  = wr[k];
        float4 x0 = xl[bq * 4 + 0][k];
        float4 x1 = xl[bq * 4 + 1][k];
        float4 x2 = xl[bq * 4 + 2][k];
        float4 x3 = xl[bq * 4 + 3][k];
        a0 += w.x * x0.x + w.y * x0.y + w.z * x0.z + w.w * x0.w;
        a1 += w.x * x1.x + w.y * x1.y + w.z * x1.z + w.w * x1.w;
        a2 += w.x * x2.x + w.y * x2.y + w.z * x2.z + w.w * x2.w;
        a3 += w.x * x3.x + w.y * x3.y + w.z * x3.z + w.w * x3.w;
    }
    const float bv = bih[g0 + gl];
    GI[(size_t)(s * BB + bq * 4 + 0) * G3 + g0 + gl] = a0 + bv;
    GI[(size_t)(s * BB + bq * 4 + 1) * G3 + g0 + gl] = a1 + bv;
    GI[(size_t)(s * BB + bq * 4 + 2) * G3 + g0 + gl] = a2 + bv;
    GI[(size_t)(s * BB + bq * 4 + 3) * G3 + g0 + gl] = a3 + bv;
}

// ---------------------------------------------------------------------------
// Kernel B: full recurrence. 32 blocks x 512 threads (8 waves, 2/SIMD).
// All matvecs (incl. attention) via fp8 MFMA; eo kept only as fp8 fragments.
// Decoder: 5 barriers/step. Encoder: 2 barriers/step.
// ---------------------------------------------------------------------------
__global__ __launch_bounds__(512, 2) void seq_kernel(
    const int*   __restrict__ inp,
    const float* __restrict__ GI,
    const float* __restrict__ eWhh, const float* __restrict__ ebhh,
    const float* __restrict__ demb,
    const float* __restrict__ Wc,   const float* __restrict__ bc,
    const float* __restrict__ dWih, const float* __restrict__ dWhh,
    const float* __restrict__ dbih, const float* __restrict__ dbhh,
    const float* __restrict__ Wo,   const float* __restrict__ bo,
    float* __restrict__ out)
{
    __shared__ unsigned long long eoF [2048];   // 16KB  eo A-frags (rows=s,K=j)
    __shared__ unsigned long long eoTF[2048];   // 16KB  eo^T A-frags (rows=j,K=s)
    __shared__ unsigned long long wc2l[8192];   // 64KB  Wc2 A-frags
    __shared__ float __attribute__((aligned(16))) gg [G3];
    __shared__ float __attribute__((aligned(16))) gi2[G3];
    __shared__ float __attribute__((aligned(16))) sc [SC];
    __shared__ float __attribute__((aligned(16))) xb [HH];
    __shared__ unsigned long long h_f8w[32];    // h  fp8 (x32), linear bytes
    __shared__ unsigned long long c_f8w[32];    // ctx fp8 (x32)
    __shared__ unsigned long long x_f8w[32];    // x   fp8 (x32)
    __shared__ unsigned long long a_f8w[8];     // attn fp8 (x64)
    __shared__ float p4[4];
    __shared__ int   tokl[TT];
    __shared__ float bo_l[TT];
    __shared__ unsigned short woF[TT * HH];     // 32KB  W_out[tok] rows, bf16

    const int b    = blockIdx.x;
    const int t    = threadIdx.x;
    const int lane = t & 63;
    const int w    = t >> 6;          // wave 0..7
    const int lg   = lane >> 4;       // k-group 0..3
    const int rr   = lane & 15;
    const bool wr0 = (rr == 0);
    const int RB   = w * 96;          // this wave's gate-row base

    if (t < TT) tokl[t] = inp[b * TT + t];
    if (t < 32) h_f8w[t] = 0ULL;
    __syncthreads();

    // one-time staging: Wc2 frags, W_out rows (bf16), b_out gather, xb
    for (int i = t; i < 8192; i += 512) {
        const int lf = i & 63, kt = (i >> 6) & 7, rt2 = i >> 9;
        const float* p = Wc + (size_t)(rt2 * 16 + (lf & 15)) * (2 * HH)
                       + HH + kt * 32 + (lf >> 4) * 8;
        wc2l[i] = pack_row8(p);
    }
    for (int i = t; i < TT * HH; i += 512) {
        const int di = i >> 8, col = i & 255;
        const float v = Wo[(size_t)tokl[di] * HH + col];
        const unsigned bits = __float_as_uint(v);
        woF[i] = (unsigned short)((bits + 0x7FFFu + ((bits >> 16) & 1u)) >> 16);
    }
    if (t < TT) bo_l[t] = bo[tokl[t]];

    float bi0=0,bi1=0,bi2=0,bh0=0,bh1=0,bh2=0,eb0=0,eb1=0,eb2=0;
    float h_prev = 0.f;
    if (t < HH) {
        bi0 = dbih[t]; bi1 = dbih[HH+t]; bi2 = dbih[2*HH+t];
        bh0 = dbhh[t]; bh1 = dbhh[HH+t]; bh2 = dbhh[2*HH+t];
        eb0 = ebhh[t]; eb1 = ebhh[HH+t]; eb2 = ebhh[2*HH+t];
        float a = bc[t];
        const float4* wrp = (const float4*)(Wc + (size_t)t * (2 * HH));
        const float4* es  = (const float4*)(demb + HH);     // SOS_INDEX = 1
        #pragma unroll
        for (int k = 0; k < HH / 4; ++k) {
            float4 wv = wrp[k], e = es[k];
            a += wv.x * e.x + wv.y * e.y + wv.z * e.z + wv.w * e.w;
        }
        xb[t] = a;
    }

    // ================= encoder: 64 steps, 2 barriers each =================
    {
        DECL6(aE, eWhh)
        float g0 = 0.f, g1 = 0.f, g2 = 0.f;
        if (t < HH) {
            const float* gp = GI + (size_t)b * G3;
            g0 = gp[t]; g1 = gp[HH + t]; g2 = gp[2 * HH + t];
        }
        for (int s = 0; s < SC; ++s) {
            __syncthreads();                    // h_f8 ready
            { LDB(h_f8w) DO6(aE, gg) }          // gh = Whh.h (raw x512)
            __syncthreads();                    // gg ready
            if (t < HH) {
                float gn0 = 0.f, gn1 = 0.f, gn2 = 0.f;
                if (s + 1 < SC) {
                    const float* gp = GI + (size_t)((s + 1) * BB + b) * G3;
                    gn0 = gp[t]; gn1 = gp[HH + t]; gn2 = gp[2 * HH + t];
                }
                float r = sigmf(g0 + gg[t] * INV512 + eb0);
                float z = sigmf(g1 + gg[HH + t] * INV512 + eb1);
                float n = tanhf(g2 + r * (gg[2 * HH + t] * INV512 + eb2));
                float hn = (1.f - z) * n + z * h_prev;
                h_prev = hn;
                const unsigned pk = CVTPK(hn * VSCL, hn * VSCL, 0, false);
                ((char*)h_f8w)[t] = (char)pk;
                // eo fragment bytes (this step's eo[s][t] = hn)
                const int wdF = ((s >> 4) * 8 + (t >> 5)) * 64 + (s & 15) + (((t >> 3) & 3) << 4);
                ((char*)eoF)[wdF * 8 + (t & 7)] = (char)pk;
                const int wdT = ((t >> 4) * 2 + (s >> 5)) * 64 + (t & 15) + (((s >> 3) & 3) << 4);
                ((char*)eoTF)[wdT * 8 + (s & 7)] = (char)pk;
                g0 = gn0; g1 = gn1; g2 = gn2;
            }
        }
    }

    // ================= decoder fragments =================
    DECL6(aI, dWih)
    DECL6(aH, dWhh)

    // ================= decoder: 64 steps, 5 barriers each =================
    for (int di = 0; di < TT; ++di) {
        __syncthreads();                        // h_f8 + p4 ready
        // --- A: gh (all waves) + D1 scores (waves 0-3) + D7-finish(prev) ---
        {
            LDB(h_f8w)
            if (t == 256 && di > 0) {
                const float lgt = p4[0] + p4[1] + p4[2] + p4[3];
                out[1 + b * TT + (di - 1)] = sigmf(lgt + bo_l[di - 1]);
            }
            DO6(aH, gg)
            if (w < 4) {                        // scores tile st = w
                f32x4 acc = {0.f, 0.f, 0.f, 0.f};
                const unsigned long long* ef = eoF + (size_t)w * 512;
                acc = MFMA8((long)ef[0 * 64 + lane], bq0, acc);
                acc = MFMA8((long)ef[1 * 64 + lane], bq1, acc);
                acc = MFMA8((long)ef[2 * 64 + lane], bq2, acc);
                acc = MFMA8((long)ef[3 * 64 + lane], bq3, acc);
                acc = MFMA8((long)ef[4 * 64 + lane], bq4, acc);
                acc = MFMA8((long)ef[5 * 64 + lane], bq5, acc);
                acc = MFMA8((long)ef[6 * 64 + lane], bq6, acc);
                acc = MFMA8((long)ef[7 * 64 + lane], bq7, acc);
                if (wr0) *(f32x4*)(sc + w * 16 + (lg << 2)) = acc;
            }
        }
        __syncthreads();
        // --- B: softmax + D3 ctx (wave 0 solo, no extra barrier) ---
        if (w == 0) {
            float v = sc[lane] * INV1024;
            float m = v;
            #pragma unroll
            for (int o = 32; o; o >>= 1) m = fmaxf(m, __shfl_xor(m, o));
            float e = __expf(v - m), su = e;
            #pragma unroll
            for (int o = 32; o; o >>= 1) su += __shfl_xor(su, o);
            const float at = e / su;
            const unsigned pk = CVTPK(at * ASCL, at * ASCL, 0, false);
            ((char*)a_f8w)[lane] = (char)pk;
            asm volatile("s_waitcnt lgkmcnt(0)" ::: "memory");
            __builtin_amdgcn_sched_barrier(0);
            const long ba0 = (long)a_f8w[lg], ba1 = (long)a_f8w[4 | lg];
            #pragma unroll
            for (int jt = 0; jt < 16; ++jt) {
                f32x4 acc = {0.f, 0.f, 0.f, 0.f};
                acc = MFMA8((long)eoTF[(jt * 2 + 0) * 64 + lane], ba0, acc);
                acc = MFMA8((long)eoTF[(jt * 2 + 1) * 64 + lane], ba1, acc);
                if (wr0) {
                    unsigned pc = 0;
                    pc = CVTPK(acc[0] * CPACK, acc[1] * CPACK, pc, false);
                    pc = CVTPK(acc[2] * CPACK, acc[3] * CPACK, pc, true);
                    *(unsigned*)((char*)c_f8w + jt * 16 + (lg << 2)) = pc;
                }
            }
        }
        __syncthreads();
        // --- C: x = relu(xb + Wc2.ctx), pack x_f8 inline (2 tiles/wave) ---
        {
            LDB(c_f8w)
            #pragma unroll
            for (int ii = 0; ii < 2; ++ii) {
                const int jt = 2 * w + ii;
                f32x4 acc = {0.f, 0.f, 0.f, 0.f};
                const unsigned long long* wrow = wc2l + (size_t)jt * 512;
                acc = MFMA8((long)wrow[0 * 64 + lane], bq0, acc);
                acc = MFMA8((long)wrow[1 * 64 + lane], bq1, acc);
                acc = MFMA8((long)wrow[2 * 64 + lane], bq2, acc);
                acc = MFMA8((long)wrow[3 * 64 + lane], bq3, acc);
                acc = MFMA8((long)wrow[4 * 64 + lane], bq4, acc);
                acc = MFMA8((long)wrow[5 * 64 + lane], bq5, acc);
                acc = MFMA8((long)wrow[6 * 64 + lane], bq6, acc);
                acc = MFMA8((long)wrow[7 * 64 + lane], bq7, acc);
                if (wr0) {
                    const int j0 = jt * 16 + (lg << 2);
                    const float4 xbv = *(float4*)(xb + j0);
                    const float v0 = fmaxf(acc[0] * INV512 + xbv.x, 0.f);
                    const float v1 = fmaxf(acc[1] * INV512 + xbv.y, 0.f);
                    const float v2 = fmaxf(acc[2] * INV512 + xbv.z, 0.f);
                    const float v3 = fmaxf(acc[3] * INV512 + xbv.w, 0.f);
                    unsigned pc = 0;
                    pc = CVTPK(v0 * VSCL, v1 * VSCL, pc, false);
                    pc = CVTPK(v2 * VSCL, v3 * VSCL, pc, true);
                    *(unsigned*)((char*)x_f8w + j0) = pc;
                }
            }
        }
        __syncthreads();
        // --- D: gi = Wih.x (raw x512) ---
        { LDB(x_f8w) DO6(aI, gi2) }
        __syncthreads();
        // --- E: GRU update + h_f8 pack + D7 partial dot ---
        if (t < HH) {
            float r = sigmf((gi2[t] + gg[t]) * INV512 + bi0 + bh0);
            float z = sigmf((gi2[HH + t] + gg[HH + t]) * INV512 + bi1 + bh1);
            float n = tanhf(gi2[2 * HH + t] * INV512 + bi2 +
                            r * (gg[2 * HH + t] * INV512 + bh2));
            const float hn = (1.f - z) * n + z * h_prev;
            h_prev = hn;
            const unsigned pk = CVTPK(hn * VSCL, hn * VSCL, 0, false);
            ((char*)h_f8w)[t] = (char)pk;
            const unsigned short wu = woF[(di << 8) + t];
            float part = hn * __uint_as_float(((unsigned)wu) << 16);
            #pragma unroll
            for (int o = 32; o; o >>= 1) part += __shfl_xor(part, o);
            if (lane == 0) p4[w] = part;
        }
    }
    __syncthreads();
    if (t == 256) {
        const float lgt = p4[0] + p4[1] + p4[2] + p4[3];
        out[1 + b * TT + (TT - 1)] = sigmf(lgt + bo_l[TT - 1]);
    }
}

// ---------------------------------------------------------------------------
// Kernel C: BCE loss over the 2048 gathered probabilities -> out[0]
// ---------------------------------------------------------------------------
__global__ __launch_bounds__(256) void loss_kernel(const int* __restrict__ ts,
                                                   float* __restrict__ out)
{
    __shared__ float red[4];
    const int t = threadIdx.x;
    const float tv = (float)ts[0];
    float sum = 0.f;
    for (int i = t; i < BB * TT; i += 256) {
        float p = out[1 + i];
        float lp  = fmaxf(__logf(p), -100.f);
        float l1p = fmaxf(__logf(1.f - p), -100.f);
        sum += tv * lp + (1.f - tv) * l1p;
    }
    #pragma unroll
    for (int off = 32; off; off >>= 1) sum += __shfl_xor(sum, off);
    if ((t & 63) == 0) red[t >> 6] = sum;
    __syncthreads();
    if (t == 0) out[0] = -(red[0] + red[1] + red[2] + red[3]) / (float)(BB * TT);
}

// ---------------------------------------------------------------------------
extern "C" void kernel_launch(void* const* d_in, const int* in_sizes, int n_in,
                              void* d_out, int out_size, void* d_ws, size_t ws_size,
                              hipStream_t stream)
{
    const int*   ctx     = (const int*)d_in[0];
    const int*   inp     = (const int*)d_in[1];
    const int*   ts      = (const int*)d_in[2];
    const float* enc_emb = (const float*)d_in[3];
    const float* eWih    = (const float*)d_in[4];
    const float* eWhh    = (const float*)d_in[5];
    const float* ebih    = (const float*)d_in[6];
    const float* ebhh    = (const float*)d_in[7];
    const float* demb    = (const float*)d_in[8];
    const float* Wc      = (const float*)d_in[9];
    const float* bc      = (const float*)d_in[10];
    const float* dWih    = (const float*)d_in[11];
    const float* dWhh    = (const float*)d_in[12];
    const float* dbih    = (const float*)d_in[13];
    const float* dbhh    = (const float*)d_in[14];
    const float* Wo      = (const float*)d_in[15];
    const float* bo      = (const float*)d_in[16];
    float* out = (float*)d_out;
    float* GI  = (float*)d_ws;   // 64*32*768 f32 = 6.29 MB (proven footprint)

    hipLaunchKernelGGL(gi_pre_kernel, dim3(SC * 24), dim3(256), 0, stream,
                       ctx, enc_emb, eWih, ebih, GI);
    hipLaunchKernelGGL(seq_kernel, dim3(BB), dim3(512), 0, stream,
                       inp, GI, eWhh, ebhh, demb, Wc, bc,
                       dWih, dWhh, dbih, dbhh, Wo, bo, out);
    hipLaunchKernelGGL(loss_kernel, dim3(1), dim3(256), 0, stream, ts, out);
}